// Round 5
// baseline (607.775 us; speedup 1.0000x reference)
//
#include <hip/hip_runtime.h>
#include <stdint.h>

typedef __bf16 bf8 __attribute__((ext_vector_type(8)));
typedef float f4 __attribute__((ext_vector_type(4)));
typedef unsigned short us4 __attribute__((ext_vector_type(4)));
typedef unsigned short us8 __attribute__((ext_vector_type(8)));
typedef unsigned short u16x4 __attribute__((ext_vector_type(4)));
typedef unsigned short u16x8 __attribute__((ext_vector_type(8)));
typedef float fl4 __attribute__((ext_vector_type(4)));

#define NB 4096      // batch
#define NS 10        // context tokens
#define NE 512       // embed
#define NH 2048      // hidden

__device__ __forceinline__ unsigned short f2bf(float f) {
    uint32_t u = __builtin_bit_cast(uint32_t, f);
    u += 0x7FFFu + ((u >> 16) & 1u);
    return (unsigned short)(u >> 16);
}
__device__ __forceinline__ __bf16 bfb(unsigned short u) { return __builtin_bit_cast(__bf16, u); }

__device__ __forceinline__ void gl_lds16(const void* g, void* l) {
    __builtin_amdgcn_global_load_lds((const __attribute__((address_space(1))) uint32_t*)g,
                                     (__attribute__((address_space(3))) uint32_t*)l, 16, 0, 0);
}

// ---------------- prep: gather emb rows + cast weights, all -> bf16 ----------------
__global__ __launch_bounds__(256) void prep_kernel(
    const int* __restrict__ t, const int* __restrict__ c, const float* __restrict__ emb,
    const float* __restrict__ Wq, const float* __restrict__ Wk, const float* __restrict__ Wv,
    unsigned short* __restrict__ Xt, unsigned short* __restrict__ Xc,
    unsigned short* __restrict__ wQ, unsigned short* __restrict__ wK, unsigned short* __restrict__ wV)
{
    int v = blockIdx.x * 256 + threadIdx.x;
    const float* src;
    unsigned short* dst;
    if (v < 524288) {
        int e4 = v << 2; int row = e4 >> 9;
        src = emb + (size_t)t[row] * NE + (e4 & 511);
        dst = Xt + e4;
    } else if (v < 5767168) {
        int vv = v - 524288; int e4 = vv << 2; int row = e4 >> 9;
        src = emb + (size_t)c[row] * NE + (e4 & 511);
        dst = Xc + e4;
    } else {
        int vv = v - 5767168; int which = vv >> 18; int e4 = (vv & 262143) << 2;
        src = (which == 0 ? Wq : (which == 1 ? Wk : Wv)) + e4;
        dst = (which == 0 ? wQ : (which == 1 ? wK : wV)) + e4;
    }
    fl4 f = *(const fl4*)src;
    us4 o;
    o[0] = f2bf(f[0]); o[1] = f2bf(f[1]); o[2] = f2bf(f[2]); o[3] = f2bf(f[3]);
    *(us4*)dst = o;
}

// ---------------- GEMM: Y[m,n] = sum_k A[m,k]*W[n,k] + bias[n] ----------------
// 128x128 tile, BK=64, 4 waves. T1 XCD swizzle (round-4 verified: FETCH 350->99MB).
// V-segment (id>=6144) writes Vb in attn-friendly [token][d][q] layout:
//   B-tile row ln holds wV row nmap(ln) = (ln>>3)*128 + nt*8 + (ln&7)  (per-lane
//   pre-permuted gl_lds source, m173); epilogue writes elem (m, d=nt*8+(ln&7), q=ln>>3)
//   at Vb[m*2048 + d*16 + q]; bias indexed at nmap(ln).
__global__ __launch_bounds__(256, 2) void gemm_all(
    const unsigned short* __restrict__ Xt, const unsigned short* __restrict__ Xc,
    const unsigned short* __restrict__ wQ, const unsigned short* __restrict__ wK,
    const unsigned short* __restrict__ wV,
    const float* __restrict__ bq, const float* __restrict__ bk, const float* __restrict__ bv,
    unsigned short* __restrict__ Qb, unsigned short* __restrict__ Kb, unsigned short* __restrict__ Vb,
    float* __restrict__ TV)
{
    // bijective XCD swizzle: nwg = 11264 = 8 * 1408
    int oid = blockIdx.x;
    int id = (oid & 7) * 1408 + (oid >> 3);

    const unsigned short* A; const unsigned short* W; const float* bias;
    unsigned short* outb = nullptr; float* outf = nullptr;
    int tile;
    if (id < 512)       { A = Xt; W = wQ; bias = bq; outb = Qb; tile = id; }
    else if (id < 1024) { A = Xt; W = wV; bias = bv; outf = TV; tile = id - 512; }
    else if (id < 6144) { A = Xc; W = wK; bias = bk; outb = Kb; tile = id - 1024; }
    else                { A = Xc; W = wV; bias = bv; outb = Vb; tile = id - 6144; }
    bool vperm = (id >= 6144);
    int mt = tile >> 4, nt = tile & 15;
    int m0 = mt * 128, n0 = nt * 128;

    __shared__ unsigned short Asm[128 * 64];
    __shared__ unsigned short Bsm[128 * 64];

    int tid = threadIdx.x;
    int lane = tid & 63, wid = tid >> 6;
    int hi = lane >> 4, lo = lane & 15;
    int wm = (wid >> 1) * 64, wn = (wid & 1) * 64;

    f4 acc[4][4] = {};

    for (int ks = 0; ks < 8; ++ks) {
        int k0 = ks * 64;
        for (int i = 0; i < 4; ++i) {
            int ci = (i << 8) + tid;            // 0..1023
            int row = ci >> 3, ch = ci & 7;
            const unsigned short* ga = A + (size_t)(m0 + row) * NE + k0 + ch * 8;
            gl_lds16(ga, Asm + ((i << 8) + (tid & ~63)) * 8);
        }
        for (int i = 0; i < 4; ++i) {
            int ci = (i << 8) + tid;
            int row = ci >> 3, ch = ci & 7;
            int grow = vperm ? (((row >> 3) << 7) + (nt << 3) + (row & 7)) : (n0 + row);
            const unsigned short* gb = W + (size_t)grow * NE + k0 + ch * 8;
            gl_lds16(gb, Bsm + ((i << 8) + (tid & ~63)) * 8);
        }
        __syncthreads();
        for (int kk = 0; kk < 2; ++kk) {
            bf8 a[4], b[4];
            for (int mi = 0; mi < 4; ++mi)
                a[mi] = *(const bf8*)&Asm[(wm + mi * 16 + lo) * 64 + kk * 32 + hi * 8];
            for (int ni = 0; ni < 4; ++ni)
                b[ni] = *(const bf8*)&Bsm[(wn + ni * 16 + lo) * 64 + kk * 32 + hi * 8];
            for (int mi = 0; mi < 4; ++mi)
                for (int ni = 0; ni < 4; ++ni)
                    acc[mi][ni] = __builtin_amdgcn_mfma_f32_16x16x32_bf16(a[mi], b[ni], acc[mi][ni], 0, 0, 0);
        }
        __syncthreads();
    }

    // epilogue: D row = hi*4+r (m), col = lo (n)  [m89-verified C/D layout]
    if (vperm) {
        for (int ni = 0; ni < 4; ++ni) {
            int ln = wn + ni * 16 + lo;
            int q = ln >> 3, d = (nt << 3) + (ln & 7);
            float bb = bias[q * 128 + d];
            for (int mi = 0; mi < 4; ++mi)
                for (int r = 0; r < 4; ++r) {
                    int m = m0 + wm + mi * 16 + hi * 4 + r;
                    outb[(size_t)m * NH + d * 16 + q] = f2bf(acc[mi][ni][r] + bb);
                }
        }
    } else {
        for (int mi = 0; mi < 4; ++mi)
            for (int ni = 0; ni < 4; ++ni) {
                int n = n0 + wn + ni * 16 + lo;
                float bb = bias[n];
                for (int r = 0; r < 4; ++r) {
                    int m = m0 + wm + mi * 16 + hi * 4 + r;
                    float vv = acc[mi][ni][r] + bb;
                    if (outb) outb[(size_t)m * NH + n] = f2bf(vv);
                    else      outf[(size_t)m * NH + n] = vv;
                }
            }
    }
}

// ---------------- attention v3: 1 wave per b, s-pairs, pipelined, [d][q] V ----------------
// QK (swapped, round-2 verified): lane(hi,lo) holds score(q=4hi+r, p=lo).
// PV paired MFMA: k-slot (hi,e) <-> (token=e>=4, q=4hi+(e&3)).
//   A slot e = w_tok[q][p=lo] (lane-local from softmax);
//   B slot e = V_tok[q][d'=tt*16+lo] = ds_read_b64 at [d'][q] layout (linear, conflict-free).
// Pipeline: V(p+1) via gl_lds + K_A(p+1) issued mid-iter, hidden under softmax+PV;
// kB just-in-time after vmcnt(0) so the top wait never includes it.
__global__ __launch_bounds__(256, 4) void attn_kernel(
    const unsigned short* __restrict__ Qb, const unsigned short* __restrict__ Kb,
    const unsigned short* __restrict__ Vb, float* __restrict__ CV)
{
    __shared__ unsigned short Vl[4][4096];   // per-wave [2 tokens][128 d][16 q]
    int tid = threadIdx.x, lane = tid & 63, wid = tid >> 6;
    int hi = lane >> 4, lo = lane & 15;
    int b = blockIdx.x * 4 + wid;
    unsigned short* Vlw = &Vl[wid][0];

    const unsigned short* qrow = Qb + (size_t)b * NH;
    bf8 qf[4];
#pragma unroll
    for (int kk = 0; kk < 4; ++kk)
        qf[kk] = *(const bf8*)&qrow[lo * 128 + kk * 32 + hi * 8];

    const unsigned short* Vbase = Vb + (size_t)b * NS * NH;
    const unsigned short* Kbase = Kb + (size_t)b * NS * NH;

    f4 acc[8] = {};
    const float sc = 0.08838834764831845f;   // 1/sqrt(128)

    // prologue: stage V pair 0 (linear copy of two [d][q] rows), K token 0 -> regs
#pragma unroll
    for (int it = 0; it < 8; ++it)
        gl_lds16(Vbase + it * 512 + lane * 8, Vlw + it * 512);
    bf8 kA[4], kB[4];
#pragma unroll
    for (int kk = 0; kk < 4; ++kk)
        kA[kk] = *(const bf8*)&Kbase[lo * 128 + kk * 32 + hi * 8];

#pragma unroll
    for (int p = 0; p < 5; ++p) {
        asm volatile("s_waitcnt vmcnt(0)" ::: "memory");   // V(p) in LDS, kA(p) landed
        // just-in-time K token 2p+1 (issued after the wait so top stall excludes it)
        const unsigned short* kb1 = Kbase + (size_t)(2 * p + 1) * NH;
#pragma unroll
        for (int kk = 0; kk < 4; ++kk)
            kB[kk] = *(const bf8*)&kb1[lo * 128 + kk * 32 + hi * 8];

        f4 st0 = {}, st1 = {};
#pragma unroll
        for (int kk = 0; kk < 4; ++kk)
            st0 = __builtin_amdgcn_mfma_f32_16x16x32_bf16(kA[kk], qf[kk], st0, 0, 0, 0);
#pragma unroll
        for (int kk = 0; kk < 4; ++kk)
            st1 = __builtin_amdgcn_mfma_f32_16x16x32_bf16(kB[kk], qf[kk], st1, 0, 0, 0);

        // PV operand reads: one linear b64 per (token,tt) — 512B/wave/instr, 2-way banks
        u16x4 r0[8], r1[8];
#pragma unroll
        for (int tt = 0; tt < 8; ++tt) {
            r0[tt] = *(const u16x4*)&Vlw[tt * 256 + lo * 16 + hi * 4];
            r1[tt] = *(const u16x4*)&Vlw[2048 + tt * 256 + lo * 16 + hi * 4];
        }
        asm volatile("s_waitcnt lgkmcnt(0)" ::: "memory"); // reads done before overwrite

        if (p < 4) {   // stage pair p+1: overlaps softmax + PV MFMA below
            const unsigned short* vn = Vbase + (size_t)(2 * p + 2) * NH;
            const unsigned short* kn = Kbase + (size_t)(2 * p + 2) * NH;
#pragma unroll
            for (int it = 0; it < 8; ++it)
                gl_lds16(vn + it * 512 + lane * 8, Vlw + it * 512);
#pragma unroll
            for (int kk = 0; kk < 4; ++kk)
                kA[kk] = *(const bf8*)&kn[lo * 128 + kk * 32 + hi * 8];
        }

        // softmax over q, per token (round-2 verified reduction)
        float e0 = st0[0] * sc, e1 = st0[1] * sc, e2 = st0[2] * sc, e3 = st0[3] * sc;
        float mx = fmaxf(fmaxf(e0, e1), fmaxf(e2, e3));
        mx = fmaxf(mx, __shfl_xor(mx, 16));
        mx = fmaxf(mx, __shfl_xor(mx, 32));
        float a0 = __expf(e0 - mx), a1 = __expf(e1 - mx), a2 = __expf(e2 - mx), a3 = __expf(e3 - mx);
        float sm = a0 + a1 + a2 + a3;
        sm += __shfl_xor(sm, 16);
        sm += __shfl_xor(sm, 32);
        float inv0 = 1.0f / sm;

        float f0 = st1[0] * sc, f1 = st1[1] * sc, f2 = st1[2] * sc, f3 = st1[3] * sc;
        float my = fmaxf(fmaxf(f0, f1), fmaxf(f2, f3));
        my = fmaxf(my, __shfl_xor(my, 16));
        my = fmaxf(my, __shfl_xor(my, 32));
        float b0 = __expf(f0 - my), b1 = __expf(f1 - my), b2 = __expf(f2 - my), b3 = __expf(f3 - my);
        float sn = b0 + b1 + b2 + b3;
        sn += __shfl_xor(sn, 16);
        sn += __shfl_xor(sn, 32);
        float inv1 = 1.0f / sn;

        bf8 ap;
        ap[0] = (__bf16)(a0 * inv0); ap[1] = (__bf16)(a1 * inv0);
        ap[2] = (__bf16)(a2 * inv0); ap[3] = (__bf16)(a3 * inv0);
        ap[4] = (__bf16)(b0 * inv1); ap[5] = (__bf16)(b1 * inv1);
        ap[6] = (__bf16)(b2 * inv1); ap[7] = (__bf16)(b3 * inv1);

#pragma unroll
        for (int tt = 0; tt < 8; ++tt) {
            u16x8 cat = __builtin_shufflevector(r0[tt], r1[tt], 0, 1, 2, 3, 4, 5, 6, 7);
            bf8 bv_ = __builtin_bit_cast(bf8, cat);
            acc[tt] = __builtin_amdgcn_mfma_f32_16x16x32_bf16(ap, bv_, acc[tt], 0, 0, 0);
        }
    }

    float* out = CV + (size_t)b * NH;
#pragma unroll
    for (int tt = 0; tt < 8; ++tt)
#pragma unroll
        for (int r = 0; r < 4; ++r)
            out[(hi * 4 + r) * 128 + tt * 16 + lo] = acc[tt][r];
}

// ---------------- launch ----------------
extern "C" void kernel_launch(void* const* d_in, const int* in_sizes, int n_in,
                              void* d_out, int out_size, void* d_ws, size_t ws_size,
                              hipStream_t stream) {
    const int*   t   = (const int*)d_in[0];
    const int*   c   = (const int*)d_in[1];
    const float* emb = (const float*)d_in[2];
    const float* Wq  = (const float*)d_in[3];
    const float* bq  = (const float*)d_in[4];
    const float* Wk  = (const float*)d_in[5];
    const float* bk  = (const float*)d_in[6];
    const float* Wv  = (const float*)d_in[7];
    const float* bv  = (const float*)d_in[8];
    float* out = (float*)d_out;

    char* ws = (char*)d_ws;
    unsigned short* Xt = (unsigned short*)(ws);                 //  4,194,304 B
    unsigned short* Xc = (unsigned short*)(ws + 4194304);       // 41,943,040 B
    unsigned short* wQ = (unsigned short*)(ws + 46137344);      //  2,097,152 B
    unsigned short* wK = (unsigned short*)(ws + 48234496);      //  2,097,152 B
    unsigned short* wV = (unsigned short*)(ws + 50331648);      //  2,097,152 B
    unsigned short* Qb = (unsigned short*)(ws + 52428800);      // 16,777,216 B
    unsigned short* Kb = (unsigned short*)(ws + 69206016);      // 167,772,160 B
    unsigned short* Vb = (unsigned short*)(ws + 236978176);     // 167,772,160 B -> end 404,750,336

    prep_kernel<<<25600, 256, 0, stream>>>(t, c, emb, Wq, Wk, Wv, Xt, Xc, wQ, wK, wV);
    gemm_all<<<11264, 256, 0, stream>>>(Xt, Xc, wQ, wK, wV, bq, bk, bv, Qb, Kb, Vb, out);
    attn_kernel<<<1024, 256, 0, stream>>>(Qb, Kb, Vb, out + (size_t)NB * NH);
}